// Round 13
// baseline (228.707 us; speedup 1.0000x reference)
//
#include <hip/hip_runtime.h>

#define NN 100000
#define NE 220000
#define HD 128
#define NG 4096
#define NPE 5
#define NB_SCAN ((NN + 255) / 256)   // 391
#define NBX4 ((NN * HD / 4) / 256)   // 12500 (exact)
#define NT16 (NN / 16)               // 6250 node-tiles (exact)
#define NBGEMM 1024                  // gemm blocks (4096 waves = resident cap)
#define NBW 128                      // Wcat prep blocks
#define NBE2 14                      // emb2 blocks (3584 floats)
#define NBD ((2 * NE + 255) / 256)   // 1719 edge blocks

typedef unsigned int uint;
typedef unsigned short ushort;
typedef __attribute__((ext_vector_type(8))) short bf16x8;
typedef __attribute__((ext_vector_type(4))) float f32x4;

__device__ __forceinline__ float bf2f(uint u16) {
    return __uint_as_float(u16 << 16);
}
__device__ __forceinline__ ushort f2bf(float f) {
    uint u = __float_as_uint(f);
    u += 0x7fffu + ((u >> 16) & 1u);   // RNE
    return (ushort)(u >> 16);
}

// Prep + edge phase: Wcat (transposed bf16 W1|Wv1), emb2 = embed + bt, and the
// degree count WITH rank capture (atomic return value = slot rank -> scatter
// needs no atomics).  cnt zeroed by the preceding memset.
__global__ void k_prep0(const float* __restrict__ W1, const float* __restrict__ Wv1,
                        const float* __restrict__ embed, const float* __restrict__ bt,
                        ushort* __restrict__ Wcat, float* __restrict__ emb2,
                        const int* __restrict__ ei, const int* __restrict__ vei,
                        int* __restrict__ cnt, int* __restrict__ rank) {
    int b = blockIdx.x;
    if (b < NBW) {
        int t = b * 256 + threadIdx.x;   // 32768
        int f = t >> 7, k = t & 127;
        const float* W = (f < HD) ? W1 : Wv1;
        Wcat[t] = f2bf(W[k * HD + (f & 127)]);    // Wcat[f][k] = W[k][f]
    } else if (b < NBW + NBE2) {
        int t = (b - NBW) * 256 + threadIdx.x;
        if (t < 28 * 128) emb2[t] = embed[t] + bt[t & 127];
    } else {
        int t = (b - NBW - NBE2) * 256 + threadIdx.x;
        if (t < 2 * NE) {
            int br = t >= NE;
            int e = t - br * NE;
            const int* S = br ? vei : ei;
            rank[t] = atomicAdd(&cnt[br * NN + S[NE + e]], 1);
        }
    }
}

// Merged dispatch: blocks [0, 2*NB_SCAN) = scan1 (per-block prefix + dinv +
// y zero — needs only cnt from prep0); rest = pure streaming front (one
// float4 of x per thread, writes f32 x and bf16 xb).
__global__ void k_front_scan1(const int* __restrict__ tok, const float* __restrict__ pe,
                              const float* __restrict__ emb2,
                              const float* __restrict__ Wtr,
                              float* __restrict__ x, ushort* __restrict__ xb,
                              const int* __restrict__ cnt, int* __restrict__ off,
                              int* __restrict__ bsum, float* __restrict__ dinv,
                              float* __restrict__ y) {
    __shared__ int s[256];
    int b = blockIdx.x;
    if (b < 2 * NB_SCAN) {
        int tid = threadIdx.x;
        int gid = b * 256 + tid;
        if (gid < NG) y[gid] = 0.f;
        int br = b / NB_SCAN;
        int blk = b % NB_SCAN;
        int i = blk * 256 + tid;
        int v = (i < NN) ? cnt[br * NN + i] : 0;
        if (i < NN) dinv[br * NN + i] = rsqrtf((float)v + 1.0f);
        s[tid] = v;
        __syncthreads();
        for (int d = 1; d < 256; d <<= 1) {
            int t = (tid >= d) ? s[tid - d] : 0;
            __syncthreads();
            s[tid] += t;
            __syncthreads();
        }
        if (i < NN) off[br * NN + i] = s[tid] - v;
        if (tid == 255) bsum[br * 512 + blk] = s[255];
    } else {
        int idx = (b - 2 * NB_SCAN) * 256 + threadIdx.x;
        int n = idx >> 5, q = idx & 31;
        int t = tok[n];
        float4 acc = ((const float4*)(emb2 + (size_t)t * HD))[q];
        const float* pen = pe + n * NPE;
#pragma unroll
        for (int k = 0; k < NPE; ++k) {
            float p = pen[k];
            float4 wv = ((const float4*)(Wtr + k * HD))[q];
            acc.x += p * wv.x; acc.y += p * wv.y;
            acc.z += p * wv.z; acc.w += p * wv.w;
        }
        ((float4*)x)[idx] = acc;
        uint2 pk;
        pk.x = (uint)f2bf(acc.x) | ((uint)f2bf(acc.y) << 16);
        pk.y = (uint)f2bf(acc.z) | ((uint)f2bf(acc.w) << 16);
        ((uint2*)xb)[idx] = pk;
    }
}

// Merged dispatch: blocks [0, 2*NB_SCAN) = scan3 (cross-block prefix ->
// off2); rest = GEMM: register-resident W, grid-stride node tiles, zero
// LDS/barriers on the gemm path.
__global__ __launch_bounds__(256) void k_gemm_scan3(
        const ushort* __restrict__ xb, const ushort* __restrict__ Wt,
        ushort* __restrict__ H,
        const int* __restrict__ off, const int* __restrict__ bsum,
        const int* __restrict__ cnt, int2* __restrict__ off2) {
    __shared__ int s[256];
    int b = blockIdx.x;
    if (b < 2 * NB_SCAN) {
        int br = b / NB_SCAN;
        int blk = b % NB_SCAN;
        int tid = threadIdx.x;
        int v = 0;
        if (tid < blk) v = bsum[br * 512 + tid];
        if (tid + 256 < blk) v += bsum[br * 512 + tid + 256];
        s[tid] = v;
#pragma unroll
        for (int d = 128; d > 0; d >>= 1) {
            __syncthreads();
            if (tid < d) s[tid] += s[tid + d];
        }
        __syncthreads();
        int pre = s[0];
        int i = blk * 256 + tid;
        if (i < NN) {
            int o = off[br * NN + i] + pre;
            int2 pr;
            pr.x = o;
            pr.y = o + cnt[br * NN + i];
            off2[br * NN + i] = pr;
        }
    } else {
        int w = threadIdx.x >> 6;        // ftg = w
        int lane = threadIdx.x & 63;
        int m = lane & 15, quad = lane >> 4;
        const ushort* Wbase = Wt + ((size_t)(w * 4) * 16 + m) * 128 + quad * 8;
        bf16x8 wf[4][4];
#pragma unroll
        for (int j = 0; j < 4; ++j)
#pragma unroll
            for (int kc = 0; kc < 4; ++kc)
                wf[j][kc] = *(const bf16x8*)(Wbase + (size_t)j * 16 * 128 + kc * 32);

        for (int t = b - 2 * NB_SCAN; t < NT16; t += NBGEMM) {
            int n = t * 16 + m;                       // NN = NT16*16 exact
            const ushort* Arow = xb + (size_t)n * HD + quad * 8;
            bf16x8 xf[4];
#pragma unroll
            for (int kc = 0; kc < 4; ++kc)
                xf[kc] = *(const bf16x8*)(Arow + kc * 32);
            f32x4 acc[4] = {};
#pragma unroll
            for (int j = 0; j < 4; ++j)
#pragma unroll
                for (int kc = 0; kc < 4; ++kc)
                    acc[j] = __builtin_amdgcn_mfma_f32_16x16x32_bf16(wf[j][kc], xf[kc],
                                                                     acc[j], 0, 0, 0);
#pragma unroll
            for (int j = 0; j < 4; ++j) {
                f32x4 a = acc[j];
                uint2 pk;
                pk.x = (uint)f2bf(a[0]) | ((uint)f2bf(a[1]) << 16);
                pk.y = (uint)f2bf(a[2]) | ((uint)f2bf(a[3]) << 16);
                *(uint2*)&H[(size_t)n * 256 + (w * 4 + j) * 16 + quad * 4] = pk;
            }
        }
    }
}

// Atomic-free scatter: slot = off2[d].x + rank[e].  Ranks 0-3 are ALSO
// written to the dense per-node cache ent8[(br*NN+d)*4 + rank] — gather and
// final2 read their first 4 edges from a statically-known address (kills one
// dependent-load hop).  ent8 padding slots stay {0, 0.0} (zeroed by memset):
// coef 0.0 contributes exactly nothing.
__global__ void k_scatter(const int* __restrict__ ei, const int* __restrict__ vei,
                          const int* __restrict__ rank, const float* __restrict__ dinv,
                          const int2* __restrict__ off2, int2* __restrict__ ent,
                          int2* __restrict__ ent8) {
    int t = blockIdx.x * blockDim.x + threadIdx.x;
    if (t >= 2 * NE) return;
    int br = t >= NE;
    int e = t - br * NE;
    const int* S = br ? vei : ei;
    int s = S[e], d = S[NE + e];
    int rk = rank[t];
    int base = br * NN + d;
    int pos = off2[base].x + rk;
    int2 rec;
    rec.x = s;
    rec.y = __float_as_int(dinv[br * NN + s] * dinv[br * NN + d]);
    ent[br * NE + pos] = rec;
    if (rk < 4) ent8[base * 4 + rk] = rec;
}

// Fused gather + layer-1 epilogue. 2 nodes per wave (32 lanes x uint2 each).
// First 4 edges come from the dense ent8 cache (issued concurrently with
// off2/dinv/self-H — 2 memory hops instead of 3); ~92% of nodes (deg<=4,
// Poisson lambda=2.2) never touch ent.  Tail (deg>4) walks ent from p0+4
// (exact partition: slot = p0 + rank).  ent has +8 rec padding.
__global__ void k_gather_ep(const ushort* __restrict__ H, const float* __restrict__ dinv,
                            const int2* __restrict__ off2,
                            const int2* __restrict__ ent,
                            const int4* __restrict__ ent8,
                            const float* __restrict__ b1, const float* __restrict__ bv1,
                            const float* __restrict__ W2, const float* __restrict__ Wv2,
                            float* __restrict__ z) {
    int wid = threadIdx.x >> 6;
    int lane = threadIdx.x & 63;
    int half = lane >> 5;
    int l = lane & 31;
    int task = blockIdx.x * 8 + wid * 2 + half;
    int br = task >= NN;
    int n = task - br * NN;

    const int2* en = ent + br * NE;
    size_t hoff = (size_t)br * 128;
    int base = br * NN + n;

    // independent loads — all issue before any wait
    int4 e01 = ent8[base * 2];         // records 0,1
    int4 e23 = ent8[base * 2 + 1];     // records 2,3
    int2 pr = off2[base];
    float dv = dinv[base];
    uint2 u = *(const uint2*)(H + (size_t)n * 256 + hoff + l * 4);

    float c = dv * dv;
    float a0 = bf2f(u.x & 0xffffu) * c, a1 = bf2f(u.x >> 16) * c;
    float a2 = bf2f(u.y & 0xffffu) * c, a3 = bf2f(u.y >> 16) * c;

    // fixed 4 edges from ent8 (zero-padded: coef 0 -> no-op)
    {
        int s0 = e01.x, s1 = e01.z, s2 = e23.x, s3 = e23.z;
        float c0 = __int_as_float(e01.y), c1 = __int_as_float(e01.w);
        float c2 = __int_as_float(e23.y), c3 = __int_as_float(e23.w);
        uint2 v0 = *(const uint2*)(H + (size_t)s0 * 256 + hoff + l * 4);
        uint2 v1 = *(const uint2*)(H + (size_t)s1 * 256 + hoff + l * 4);
        uint2 v2 = *(const uint2*)(H + (size_t)s2 * 256 + hoff + l * 4);
        uint2 v3 = *(const uint2*)(H + (size_t)s3 * 256 + hoff + l * 4);
        a0 += bf2f(v0.x & 0xffffu) * c0; a1 += bf2f(v0.x >> 16) * c0;
        a2 += bf2f(v0.y & 0xffffu) * c0; a3 += bf2f(v0.y >> 16) * c0;
        a0 += bf2f(v1.x & 0xffffu) * c1; a1 += bf2f(v1.x >> 16) * c1;
        a2 += bf2f(v1.y & 0xffffu) * c1; a3 += bf2f(v1.y >> 16) * c1;
        a0 += bf2f(v2.x & 0xffffu) * c2; a1 += bf2f(v2.x >> 16) * c2;
        a2 += bf2f(v2.y & 0xffffu) * c2; a3 += bf2f(v2.y >> 16) * c2;
        a0 += bf2f(v3.x & 0xffffu) * c3; a1 += bf2f(v3.x >> 16) * c3;
        a2 += bf2f(v3.y & 0xffffu) * c3; a3 += bf2f(v3.y >> 16) * c3;
    }

    // deg>4 tail from ent (clamped 4-wide)
    int p1 = pr.y;
    for (int p = pr.x + 4; p < p1; p += 4) {
        int2 e0 = en[p], e1 = en[p + 1], e2 = en[p + 2], e3 = en[p + 3];
        int s0 = e0.x;
        int s1 = (p + 1 < p1) ? e1.x : n;
        int s2 = (p + 2 < p1) ? e2.x : n;
        int s3 = (p + 3 < p1) ? e3.x : n;
        float c0 = __int_as_float(e0.y);
        float c1 = (p + 1 < p1) ? __int_as_float(e1.y) : 0.f;
        float c2 = (p + 2 < p1) ? __int_as_float(e2.y) : 0.f;
        float c3 = (p + 3 < p1) ? __int_as_float(e3.y) : 0.f;
        uint2 v0 = *(const uint2*)(H + (size_t)s0 * 256 + hoff + l * 4);
        uint2 v1 = *(const uint2*)(H + (size_t)s1 * 256 + hoff + l * 4);
        uint2 v2 = *(const uint2*)(H + (size_t)s2 * 256 + hoff + l * 4);
        uint2 v3 = *(const uint2*)(H + (size_t)s3 * 256 + hoff + l * 4);
        a0 += bf2f(v0.x & 0xffffu) * c0; a1 += bf2f(v0.x >> 16) * c0;
        a2 += bf2f(v0.y & 0xffffu) * c0; a3 += bf2f(v0.y >> 16) * c0;
        a0 += bf2f(v1.x & 0xffffu) * c1; a1 += bf2f(v1.x >> 16) * c1;
        a2 += bf2f(v1.y & 0xffffu) * c1; a3 += bf2f(v1.y >> 16) * c1;
        a0 += bf2f(v2.x & 0xffffu) * c2; a1 += bf2f(v2.x >> 16) * c2;
        a2 += bf2f(v2.y & 0xffffu) * c2; a3 += bf2f(v2.y >> 16) * c2;
        a0 += bf2f(v3.x & 0xffffu) * c3; a1 += bf2f(v3.x >> 16) * c3;
        a2 += bf2f(v3.y & 0xffffu) * c3; a3 += bf2f(v3.y >> 16) * c3;
    }

    const float* bb = br ? bv1 : b1;
    const float* ww = br ? Wv2 : W2;
    float4 b4 = *(const float4*)&bb[l * 4];
    float4 w4 = *(const float4*)&ww[l * 4];
    float part = fmaxf(a0 + b4.x, 0.f) * w4.x + fmaxf(a1 + b4.y, 0.f) * w4.y
               + fmaxf(a2 + b4.z, 0.f) * w4.z + fmaxf(a3 + b4.w, 0.f) * w4.w;
#pragma unroll
    for (int o = 16; o > 0; o >>= 1) part += __shfl_down(part, o, 32);
    if (l == 0) z[br * NN + n] = part;
}

// Layer-2 aggregation + LDS-batched y reduction (batch is sorted).
// Same ent8 fast path as gather (coef-0 padding contributes 0*z[0] = 0).
__global__ void k_final2(const float* __restrict__ z, const float* __restrict__ dinv,
                         const int2* __restrict__ off2,
                         const int2* __restrict__ ent,
                         const int4* __restrict__ ent8,
                         const float* __restrict__ b2, const float* __restrict__ bv2,
                         const int* __restrict__ batch, float* __restrict__ y) {
    __shared__ float ybuf[256];
    __shared__ int gbase_s;
    int br = blockIdx.x >= NB_SCAN;
    int nb = blockIdx.x - br * NB_SCAN;
    int tid = threadIdx.x;
    ybuf[tid] = 0.f;
    if (tid == 0) gbase_s = batch[nb * 256];
    __syncthreads();
    int gbase = gbase_s;
    int n = nb * 256 + tid;
    if (n < NN) {
        const int2* en = ent + br * NE;
        int base = br * NN + n;
        int4 e01 = ent8[base * 2];
        int4 e23 = ent8[base * 2 + 1];
        int2 pr = off2[base];
        float dv = dinv[base];
        float acc = z[base] * dv * dv;
        {
            float c0 = __int_as_float(e01.y), c1 = __int_as_float(e01.w);
            float c2 = __int_as_float(e23.y), c3 = __int_as_float(e23.w);
            acc += c0 * z[br * NN + e01.x] + c1 * z[br * NN + e01.z]
                 + c2 * z[br * NN + e23.x] + c3 * z[br * NN + e23.z];
        }
        int p1 = pr.y;
        for (int p = pr.x + 4; p < p1; p += 4) {
            int2 e0 = en[p], e1 = en[p + 1], e2 = en[p + 2], e3 = en[p + 3];
            int s0 = e0.x;
            int s1 = (p + 1 < p1) ? e1.x : n;
            int s2 = (p + 2 < p1) ? e2.x : n;
            int s3 = (p + 3 < p1) ? e3.x : n;
            float c0 = __int_as_float(e0.y);
            float c1 = (p + 1 < p1) ? __int_as_float(e1.y) : 0.f;
            float c2 = (p + 2 < p1) ? __int_as_float(e2.y) : 0.f;
            float c3 = (p + 3 < p1) ? __int_as_float(e3.y) : 0.f;
            acc += c0 * z[br * NN + s0] + c1 * z[br * NN + s1]
                 + c2 * z[br * NN + s2] + c3 * z[br * NN + s3];
        }
        acc += br ? bv2[0] : b2[0];
        int gi = batch[n] - gbase;
        if (gi < 256) atomicAdd(&ybuf[gi], acc);
        else atomicAdd(&y[batch[n]], acc);
    }
    __syncthreads();
    float v = ybuf[tid];
    if (v != 0.f) atomicAdd(&y[gbase + tid], v);
}

extern "C" void kernel_launch(void* const* d_in, const int* in_sizes, int n_in,
                              void* d_out, int out_size, void* d_ws, size_t ws_size,
                              hipStream_t stream) {
    const int*   tok   = (const int*)d_in[0];
    const float* pe    = (const float*)d_in[1];
    const int*   ei    = (const int*)d_in[2];
    const int*   vei   = (const int*)d_in[3];
    const int*   batch = (const int*)d_in[4];
    const float* embed = (const float*)d_in[5];
    const float* Wtr   = (const float*)d_in[6];
    const float* bt    = (const float*)d_in[7];
    const float* W1    = (const float*)d_in[8];
    const float* b1    = (const float*)d_in[9];
    const float* W2    = (const float*)d_in[10];
    const float* b2    = (const float*)d_in[11];
    const float* Wv1   = (const float*)d_in[12];
    const float* bv1   = (const float*)d_in[13];
    const float* Wv2   = (const float*)d_in[14];
    const float* bv2   = (const float*)d_in[15];

    float* y = (float*)d_out;       // [NG]
    float* x = y + NG;              // [NN*HD], output 1

    char* w = (char*)d_ws;
    ushort* xb   = (ushort*)w;               w += (size_t)NN * HD * 2;
    ushort* H    = (ushort*)w;               w += (size_t)NN * 256 * 2;
    ushort* Wcat = (ushort*)w;               w += 256 * 128 * 2;
    float*  emb2 = (float*)w;                w += 28 * 128 * 4;
    float*  dinv = (float*)w;                w += 2 * NN * 4;
    float*  z    = (float*)w;                w += 2 * NN * 4;
    int*    cnt  = (int*)w;                  w += 2 * NN * 4;          // zeroed
    int2*   ent8 = (int2*)w;                 w += (size_t)2 * NN * 4 * 8;  // zeroed (adjacent)
    int*    off  = (int*)w;                  w += 2 * NN * 4;
    int*    rank = (int*)w;                  w += (size_t)2 * NE * 4;
    int2*   off2 = (int2*)w;                 w += (size_t)2 * NN * 8;
    int2*   ent  = (int2*)w;                 w += (size_t)(2 * NE + 8) * 8;  // +pad
    int*    bsum = (int*)w;                  w += 2 * 512 * 4;

    // one memset covers cnt (0.8MB) + ent8 (6.4MB, adjacent)
    hipMemsetAsync(cnt, 0, (size_t)2 * NN * 4 + (size_t)2 * NN * 4 * 8, stream);

    k_prep0<<<NBW + NBE2 + NBD, 256, 0, stream>>>(W1, Wv1, embed, bt, Wcat, emb2,
                                                  ei, vei, cnt, rank);
    k_front_scan1<<<2 * NB_SCAN + NBX4, 256, 0, stream>>>(tok, pe, emb2, Wtr, x, xb,
                                                          cnt, off, bsum, dinv, y);
    k_gemm_scan3<<<2 * NB_SCAN + NBGEMM, 256, 0, stream>>>(xb, Wcat, H,
                                                           off, bsum, cnt, off2);
    k_scatter<<<NBD, 256, 0, stream>>>(ei, vei, rank, dinv, off2, ent, ent8);
    k_gather_ep<<<2 * NN / 8, 256, 0, stream>>>(H, dinv, off2, ent, (const int4*)ent8,
                                                b1, bv1, W2, Wv2, z);
    k_final2<<<2 * NB_SCAN, 256, 0, stream>>>(z, dinv, off2, ent, (const int4*)ent8,
                                              b2, bv2, batch, y);
}

// Round 14
// 221.153 us; speedup vs baseline: 1.0342x; 1.0342x over previous
//
#include <hip/hip_runtime.h>

#define NN 100000
#define NE 220000
#define HD 128
#define NG 4096
#define NPE 5
#define NB_SCAN ((NN + 255) / 256)   // 391
#define NBX4 ((NN * HD / 4) / 256)   // 12500 (exact)
#define NT16 (NN / 16)               // 6250 node-tiles (exact)
#define NBGEMM 1024                  // gemm blocks (4096 waves = resident cap)
#define NBW 128                      // Wcat prep blocks
#define NBE2 14                      // emb2 blocks (3584 floats)
#define NBD ((2 * NE + 255) / 256)   // 1719 edge blocks

typedef unsigned int uint;
typedef unsigned short ushort;
typedef __attribute__((ext_vector_type(8))) short bf16x8;
typedef __attribute__((ext_vector_type(4))) float f32x4;

__device__ __forceinline__ float bf2f(uint u16) {
    return __uint_as_float(u16 << 16);
}
__device__ __forceinline__ ushort f2bf(float f) {
    uint u = __float_as_uint(f);
    u += 0x7fffu + ((u >> 16) & 1u);   // RNE
    return (ushort)(u >> 16);
}

// Prep + edge phase: Wcat (transposed bf16 W1|Wv1), emb2 = embed + bt, and the
// degree count WITH rank capture (atomic return value = slot rank -> scatter
// needs no atomics).  cnt zeroed by the preceding memset.
__global__ void k_prep0(const float* __restrict__ W1, const float* __restrict__ Wv1,
                        const float* __restrict__ embed, const float* __restrict__ bt,
                        ushort* __restrict__ Wcat, float* __restrict__ emb2,
                        const int* __restrict__ ei, const int* __restrict__ vei,
                        int* __restrict__ cnt, int* __restrict__ rank) {
    int b = blockIdx.x;
    if (b < NBW) {
        int t = b * 256 + threadIdx.x;   // 32768
        int f = t >> 7, k = t & 127;
        const float* W = (f < HD) ? W1 : Wv1;
        Wcat[t] = f2bf(W[k * HD + (f & 127)]);    // Wcat[f][k] = W[k][f]
    } else if (b < NBW + NBE2) {
        int t = (b - NBW) * 256 + threadIdx.x;
        if (t < 28 * 128) emb2[t] = embed[t] + bt[t & 127];
    } else {
        int t = (b - NBW - NBE2) * 256 + threadIdx.x;
        if (t < 2 * NE) {
            int br = t >= NE;
            int e = t - br * NE;
            const int* S = br ? vei : ei;
            rank[t] = atomicAdd(&cnt[br * NN + S[NE + e]], 1);
        }
    }
}

// Merged dispatch: blocks [0, 2*NB_SCAN) = scan1 (per-block prefix + dinv +
// y zero — needs only cnt from prep0); rest = pure streaming front (one
// float4 of x per thread, writes f32 x and bf16 xb).  scan1 hides under the
// 12500 front blocks.
__global__ void k_front_scan1(const int* __restrict__ tok, const float* __restrict__ pe,
                              const float* __restrict__ emb2,
                              const float* __restrict__ Wtr,
                              float* __restrict__ x, ushort* __restrict__ xb,
                              const int* __restrict__ cnt, int* __restrict__ off,
                              int* __restrict__ bsum, float* __restrict__ dinv,
                              float* __restrict__ y) {
    __shared__ int s[256];
    int b = blockIdx.x;
    if (b < 2 * NB_SCAN) {
        int tid = threadIdx.x;
        int gid = b * 256 + tid;
        if (gid < NG) y[gid] = 0.f;
        int br = b / NB_SCAN;
        int blk = b % NB_SCAN;
        int i = blk * 256 + tid;
        int v = (i < NN) ? cnt[br * NN + i] : 0;
        if (i < NN) dinv[br * NN + i] = rsqrtf((float)v + 1.0f);
        s[tid] = v;
        __syncthreads();
        for (int d = 1; d < 256; d <<= 1) {
            int t = (tid >= d) ? s[tid - d] : 0;
            __syncthreads();
            s[tid] += t;
            __syncthreads();
        }
        if (i < NN) off[br * NN + i] = s[tid] - v;
        if (tid == 255) bsum[br * 512 + blk] = s[255];
    } else {
        int idx = (b - 2 * NB_SCAN) * 256 + threadIdx.x;
        int n = idx >> 5, q = idx & 31;
        int t = tok[n];
        float4 acc = ((const float4*)(emb2 + (size_t)t * HD))[q];
        const float* pen = pe + n * NPE;
#pragma unroll
        for (int k = 0; k < NPE; ++k) {
            float p = pen[k];
            float4 wv = ((const float4*)(Wtr + k * HD))[q];
            acc.x += p * wv.x; acc.y += p * wv.y;
            acc.z += p * wv.z; acc.w += p * wv.w;
        }
        ((float4*)x)[idx] = acc;
        uint2 pk;
        pk.x = (uint)f2bf(acc.x) | ((uint)f2bf(acc.y) << 16);
        pk.y = (uint)f2bf(acc.z) | ((uint)f2bf(acc.w) << 16);
        ((uint2*)xb)[idx] = pk;
    }
}

// Merged dispatch: blocks [0, 2*NB_SCAN) = scan3 (cross-block prefix via
// masked reduce over raw bsum totals -> off2; needs scan1 from the PREVIOUS
// dispatch); rest = GEMM: register-resident W (16 bf16x8 frags pinned once
// from the L1-hot Wcat), grid-stride node tiles, zero LDS/barriers on the
// gemm path.  A-fragments are direct bf16x8 loads from xb.
__global__ __launch_bounds__(256) void k_gemm_scan3(
        const ushort* __restrict__ xb, const ushort* __restrict__ Wt,
        ushort* __restrict__ H,
        const int* __restrict__ off, const int* __restrict__ bsum,
        const int* __restrict__ cnt, int2* __restrict__ off2) {
    __shared__ int s[256];
    int b = blockIdx.x;
    if (b < 2 * NB_SCAN) {
        int br = b / NB_SCAN;
        int blk = b % NB_SCAN;
        int tid = threadIdx.x;
        int v = 0;
        if (tid < blk) v = bsum[br * 512 + tid];
        if (tid + 256 < blk) v += bsum[br * 512 + tid + 256];
        s[tid] = v;
#pragma unroll
        for (int d = 128; d > 0; d >>= 1) {
            __syncthreads();
            if (tid < d) s[tid] += s[tid + d];
        }
        __syncthreads();
        int pre = s[0];
        int i = blk * 256 + tid;
        if (i < NN) {
            int o = off[br * NN + i] + pre;
            int2 pr;
            pr.x = o;
            pr.y = o + cnt[br * NN + i];
            off2[br * NN + i] = pr;
        }
    } else {
        int w = threadIdx.x >> 6;        // ftg = w
        int lane = threadIdx.x & 63;
        int m = lane & 15, quad = lane >> 4;
        const ushort* Wbase = Wt + ((size_t)(w * 4) * 16 + m) * 128 + quad * 8;
        bf16x8 wf[4][4];
#pragma unroll
        for (int j = 0; j < 4; ++j)
#pragma unroll
            for (int kc = 0; kc < 4; ++kc)
                wf[j][kc] = *(const bf16x8*)(Wbase + (size_t)j * 16 * 128 + kc * 32);

        for (int t = b - 2 * NB_SCAN; t < NT16; t += NBGEMM) {
            int n = t * 16 + m;                       // NN = NT16*16 exact
            const ushort* Arow = xb + (size_t)n * HD + quad * 8;
            bf16x8 xf[4];
#pragma unroll
            for (int kc = 0; kc < 4; ++kc)
                xf[kc] = *(const bf16x8*)(Arow + kc * 32);
            f32x4 acc[4] = {};
#pragma unroll
            for (int j = 0; j < 4; ++j)
#pragma unroll
                for (int kc = 0; kc < 4; ++kc)
                    acc[j] = __builtin_amdgcn_mfma_f32_16x16x32_bf16(wf[j][kc], xf[kc],
                                                                     acc[j], 0, 0, 0);
#pragma unroll
            for (int j = 0; j < 4; ++j) {
                f32x4 a = acc[j];
                uint2 pk;
                pk.x = (uint)f2bf(a[0]) | ((uint)f2bf(a[1]) << 16);
                pk.y = (uint)f2bf(a[2]) | ((uint)f2bf(a[3]) << 16);
                *(uint2*)&H[(size_t)n * 256 + (w * 4 + j) * 16 + quad * 4] = pk;
            }
        }
    }
}

// Atomic-free scatter: slot = off2[d].x + rank[e] (rank captured in k_prep0).
__global__ void k_scatter(const int* __restrict__ ei, const int* __restrict__ vei,
                          const int* __restrict__ rank, const float* __restrict__ dinv,
                          const int2* __restrict__ off2, int2* __restrict__ ent) {
    int t = blockIdx.x * blockDim.x + threadIdx.x;
    if (t >= 2 * NE) return;
    int br = t >= NE;
    int e = t - br * NE;
    const int* S = br ? vei : ei;
    int s = S[e], d = S[NE + e];
    int pos = off2[br * NN + d].x + rank[t];
    int2 rec;
    rec.x = s;
    rec.y = __float_as_int(dinv[br * NN + s] * dinv[br * NN + d]);
    ent[br * NE + pos] = rec;
}

// Fused gather + layer-1 epilogue. 2 nodes per wave (32 lanes x uint2 each).
// off2 -> ent chain hoisted to the top.  Clamped 4-wide edge batches; ent has
// +8 rec padding.
__global__ void k_gather_ep(const ushort* __restrict__ H, const float* __restrict__ dinv,
                            const int2* __restrict__ off2,
                            const int2* __restrict__ ent,
                            const float* __restrict__ b1, const float* __restrict__ bv1,
                            const float* __restrict__ W2, const float* __restrict__ Wv2,
                            float* __restrict__ z) {
    int wid = threadIdx.x >> 6;
    int lane = threadIdx.x & 63;
    int half = lane >> 5;
    int l = lane & 31;
    int task = blockIdx.x * 8 + wid * 2 + half;
    int br = task >= NN;
    int n = task - br * NN;

    const int2* en = ent + br * NE;
    size_t hoff = (size_t)br * 128;

    int2 pr = off2[br * NN + n];       // longest chain: issue first
    int p0 = pr.x, p1 = pr.y;

    float dv = dinv[br * NN + n];
    uint2 u = *(const uint2*)(H + (size_t)n * 256 + hoff + l * 4);
    float c = dv * dv;
    float a0 = bf2f(u.x & 0xffffu) * c, a1 = bf2f(u.x >> 16) * c;
    float a2 = bf2f(u.y & 0xffffu) * c, a3 = bf2f(u.y >> 16) * c;

    for (int p = p0; p < p1; p += 4) {
        int2 e0 = en[p], e1 = en[p + 1], e2 = en[p + 2], e3 = en[p + 3];
        int s0 = e0.x;
        int s1 = (p + 1 < p1) ? e1.x : n;
        int s2 = (p + 2 < p1) ? e2.x : n;
        int s3 = (p + 3 < p1) ? e3.x : n;
        float c0 = __int_as_float(e0.y);
        float c1 = (p + 1 < p1) ? __int_as_float(e1.y) : 0.f;
        float c2 = (p + 2 < p1) ? __int_as_float(e2.y) : 0.f;
        float c3 = (p + 3 < p1) ? __int_as_float(e3.y) : 0.f;
        uint2 v0 = *(const uint2*)(H + (size_t)s0 * 256 + hoff + l * 4);
        uint2 v1 = *(const uint2*)(H + (size_t)s1 * 256 + hoff + l * 4);
        uint2 v2 = *(const uint2*)(H + (size_t)s2 * 256 + hoff + l * 4);
        uint2 v3 = *(const uint2*)(H + (size_t)s3 * 256 + hoff + l * 4);
        a0 += bf2f(v0.x & 0xffffu) * c0; a1 += bf2f(v0.x >> 16) * c0;
        a2 += bf2f(v0.y & 0xffffu) * c0; a3 += bf2f(v0.y >> 16) * c0;
        a0 += bf2f(v1.x & 0xffffu) * c1; a1 += bf2f(v1.x >> 16) * c1;
        a2 += bf2f(v1.y & 0xffffu) * c1; a3 += bf2f(v1.y >> 16) * c1;
        a0 += bf2f(v2.x & 0xffffu) * c2; a1 += bf2f(v2.x >> 16) * c2;
        a2 += bf2f(v2.y & 0xffffu) * c2; a3 += bf2f(v2.y >> 16) * c2;
        a0 += bf2f(v3.x & 0xffffu) * c3; a1 += bf2f(v3.x >> 16) * c3;
        a2 += bf2f(v3.y & 0xffffu) * c3; a3 += bf2f(v3.y >> 16) * c3;
    }

    const float* bb = br ? bv1 : b1;
    const float* ww = br ? Wv2 : W2;
    float4 b4 = *(const float4*)&bb[l * 4];
    float4 w4 = *(const float4*)&ww[l * 4];
    float part = fmaxf(a0 + b4.x, 0.f) * w4.x + fmaxf(a1 + b4.y, 0.f) * w4.y
               + fmaxf(a2 + b4.z, 0.f) * w4.z + fmaxf(a3 + b4.w, 0.f) * w4.w;
#pragma unroll
    for (int o = 16; o > 0; o >>= 1) part += __shfl_down(part, o, 32);
    if (l == 0) z[br * NN + n] = part;
}

// Layer-2 aggregation + LDS-batched y reduction (batch is sorted).
__global__ void k_final2(const float* __restrict__ z, const float* __restrict__ dinv,
                         const int2* __restrict__ off2,
                         const int2* __restrict__ ent,
                         const float* __restrict__ b2, const float* __restrict__ bv2,
                         const int* __restrict__ batch, float* __restrict__ y) {
    __shared__ float ybuf[256];
    __shared__ int gbase_s;
    int br = blockIdx.x >= NB_SCAN;
    int nb = blockIdx.x - br * NB_SCAN;
    int tid = threadIdx.x;
    ybuf[tid] = 0.f;
    if (tid == 0) gbase_s = batch[nb * 256];
    __syncthreads();
    int gbase = gbase_s;
    int n = nb * 256 + tid;
    if (n < NN) {
        const int2* en = ent + br * NE;
        float dv = dinv[br * NN + n];
        float acc = z[br * NN + n] * dv * dv;
        int2 pr = off2[br * NN + n];
        int p1 = pr.y;
        for (int p = pr.x; p < p1; p += 4) {
            int2 e0 = en[p], e1 = en[p + 1], e2 = en[p + 2], e3 = en[p + 3];
            int s0 = e0.x;
            int s1 = (p + 1 < p1) ? e1.x : n;
            int s2 = (p + 2 < p1) ? e2.x : n;
            int s3 = (p + 3 < p1) ? e3.x : n;
            float c0 = __int_as_float(e0.y);
            float c1 = (p + 1 < p1) ? __int_as_float(e1.y) : 0.f;
            float c2 = (p + 2 < p1) ? __int_as_float(e2.y) : 0.f;
            float c3 = (p + 3 < p1) ? __int_as_float(e3.y) : 0.f;
            acc += c0 * z[br * NN + s0] + c1 * z[br * NN + s1]
                 + c2 * z[br * NN + s2] + c3 * z[br * NN + s3];
        }
        acc += br ? bv2[0] : b2[0];
        int gi = batch[n] - gbase;
        if (gi < 256) atomicAdd(&ybuf[gi], acc);
        else atomicAdd(&y[batch[n]], acc);
    }
    __syncthreads();
    float v = ybuf[tid];
    if (v != 0.f) atomicAdd(&y[gbase + tid], v);
}

extern "C" void kernel_launch(void* const* d_in, const int* in_sizes, int n_in,
                              void* d_out, int out_size, void* d_ws, size_t ws_size,
                              hipStream_t stream) {
    const int*   tok   = (const int*)d_in[0];
    const float* pe    = (const float*)d_in[1];
    const int*   ei    = (const int*)d_in[2];
    const int*   vei   = (const int*)d_in[3];
    const int*   batch = (const int*)d_in[4];
    const float* embed = (const float*)d_in[5];
    const float* Wtr   = (const float*)d_in[6];
    const float* bt    = (const float*)d_in[7];
    const float* W1    = (const float*)d_in[8];
    const float* b1    = (const float*)d_in[9];
    const float* W2    = (const float*)d_in[10];
    const float* b2    = (const float*)d_in[11];
    const float* Wv1   = (const float*)d_in[12];
    const float* bv1   = (const float*)d_in[13];
    const float* Wv2   = (const float*)d_in[14];
    const float* bv2   = (const float*)d_in[15];

    float* y = (float*)d_out;       // [NG]
    float* x = y + NG;              // [NN*HD], output 1

    char* w = (char*)d_ws;
    ushort* xb   = (ushort*)w;               w += (size_t)NN * HD * 2;
    ushort* H    = (ushort*)w;               w += (size_t)NN * 256 * 2;
    ushort* Wcat = (ushort*)w;               w += 256 * 128 * 2;
    float*  emb2 = (float*)w;                w += 28 * 128 * 4;
    float*  dinv = (float*)w;                w += 2 * NN * 4;
    float*  z    = (float*)w;                w += 2 * NN * 4;
    int*    cnt  = (int*)w;                  w += 2 * NN * 4;
    int*    off  = (int*)w;                  w += 2 * NN * 4;
    int*    rank = (int*)w;                  w += (size_t)2 * NE * 4;
    int2*   off2 = (int2*)w;                 w += (size_t)2 * NN * 8;
    int2*   ent  = (int2*)w;                 w += (size_t)(2 * NE + 8) * 8;  // +pad
    int*    bsum = (int*)w;                  w += 2 * 512 * 4;

    hipMemsetAsync(cnt, 0, 2 * NN * sizeof(int), stream);

    k_prep0<<<NBW + NBE2 + NBD, 256, 0, stream>>>(W1, Wv1, embed, bt, Wcat, emb2,
                                                  ei, vei, cnt, rank);
    k_front_scan1<<<2 * NB_SCAN + NBX4, 256, 0, stream>>>(tok, pe, emb2, Wtr, x, xb,
                                                          cnt, off, bsum, dinv, y);
    k_gemm_scan3<<<2 * NB_SCAN + NBGEMM, 256, 0, stream>>>(xb, Wcat, H,
                                                           off, bsum, cnt, off2);
    k_scatter<<<NBD, 256, 0, stream>>>(ei, vei, rank, dinv, off2, ent);
    k_gather_ep<<<2 * NN / 8, 256, 0, stream>>>(H, dinv, off2, ent,
                                                b1, bv1, W2, Wv2, z);
    k_final2<<<2 * NB_SCAN, 256, 0, stream>>>(z, dinv, off2, ent,
                                              b2, bv2, batch, y);
}